// Round 5
// baseline (244.030 us; speedup 1.0000x reference)
//
#include <hip/hip_runtime.h>
#include <hip/hip_bf16.h>

// PositionalEncoding: out[b,s,d] = x[b,s,d] + pe[s,d]
// x: [B=8, S=4096, D=1024] float32.
//
// R1: 8-batch loop, compiler serialized loads (24 VGPR) -> 2.28 TB/s.
// R3: 1 float4/thread + NT store -> ~70 us. No per-wave read MLP.
// R4: 4 "independent" loads -> compiler sank them anyway (VGPR=16), 2.39 TB/s.
// R5: force the load cluster with sched_barrier(0). 8 global_load_dwordx4
//     issued back-to-back per thread (one (s,d), all 8 batches -> PE once),
//     then transcendentals hide latency, then 8 NT stores.

#define PE_S 4096
#define PE_D 1024
#define N4      (8 * PE_S * PE_D / 4)     // 8,388,608 float4 elements
#define NTHREAD (N4 / 8)                  // 1,048,576 threads
#define STRIDE4 (PE_S * PE_D / 4)         // one batch, in float4 units

typedef float f32x4 __attribute__((ext_vector_type(4)));

__global__ __launch_bounds__(256) void PositionalEncoding_84095459656362_kernel(
    const float* __restrict__ x, float* __restrict__ out) {
    const int i  = blockIdx.x * blockDim.x + threadIdx.x;   // [0, S*D/4)
    const int d4 = (i & (PE_D / 4 - 1)) << 2;               // d base: 0..1020
    const int s  = i >> 8;                                  // 0..4095

    const f32x4* xp = (const f32x4*)x + i;
    f32x4*       op = (f32x4*)out + i;

    // Issue all 8 loads; sched_barrier(0) forbids the scheduler from sinking
    // them to their uses (R1/R4 failure mode).
    f32x4 v0 = xp[0 * STRIDE4];
    f32x4 v1 = xp[1 * STRIDE4];
    f32x4 v2 = xp[2 * STRIDE4];
    f32x4 v3 = xp[3 * STRIDE4];
    f32x4 v4 = xp[4 * STRIDE4];
    f32x4 v5 = xp[5 * STRIDE4];
    f32x4 v6 = xp[6 * STRIDE4];
    f32x4 v7 = xp[7 * STRIDE4];
    __builtin_amdgcn_sched_barrier(0);

    // angle(k) = s * 10000^(-k/S) = s * exp2(k*c), c = -log2(10000)/4096
    const float c  = -0.0032440703857f;
    const float r1 = 0.99775390625f;                         // 10000^(-1/4096)
    const float a0 = (float)s * __builtin_exp2f((float)(d4 >> 1) * c);
    const float a1 = a0 * r1;

    float s0, c0, s1, c1;
    __sincosf(a0, &s0, &c0);   // d even -> sin, d odd -> cos
    __sincosf(a1, &s1, &c1);
    f32x4 pe;
    pe.x = s0; pe.y = c0; pe.z = s1; pe.w = c1;

    __builtin_nontemporal_store(v0 + pe, op + 0 * STRIDE4);
    __builtin_nontemporal_store(v1 + pe, op + 1 * STRIDE4);
    __builtin_nontemporal_store(v2 + pe, op + 2 * STRIDE4);
    __builtin_nontemporal_store(v3 + pe, op + 3 * STRIDE4);
    __builtin_nontemporal_store(v4 + pe, op + 4 * STRIDE4);
    __builtin_nontemporal_store(v5 + pe, op + 5 * STRIDE4);
    __builtin_nontemporal_store(v6 + pe, op + 6 * STRIDE4);
    __builtin_nontemporal_store(v7 + pe, op + 7 * STRIDE4);
}

extern "C" void kernel_launch(void* const* d_in, const int* in_sizes, int n_in,
                              void* d_out, int out_size, void* d_ws, size_t ws_size,
                              hipStream_t stream) {
    const float* x = (const float*)d_in[0];
    float* out = (float*)d_out;
    PositionalEncoding_84095459656362_kernel<<<NTHREAD / 256, 256, 0, stream>>>(x, out);
}